// Round 8
// baseline (204.357 us; speedup 1.0000x reference)
//
#include <hip/hip_runtime.h>

#define Bsz 128
#define Cd 81
#define Md 24
#define Nd 361
#define NAd 1805
#define RPW 16                    // na-rows per tile / rows per chunk
#define NT 113                    // na tiles (112 full + 1 ragged, na0=1789)
#define NBLK_ASSIGN 48            // 48 x 64 = 3072 objects, one per thread
#define NBLK_CLS (NT*16)          // 1808 cls blocks: (tile t, b-group g of 8)
#define NBLK_TOT (NBLK_ASSIGN + NBLK_CLS)   // 1856
#define NOBJ (Bsz*Md)             // 3072
#define EPSF 1e-7f
#define IOU_THRF 0.6f

// ws float layout:
//   [0 .. 1805)        corr[NAd]      assign CE corrections (memset)
//   [1824 .. 3629)     gt[NAd]        (memset)
//   [3648 .. 3652)     acc: 0=noobj-cancel, 1=obj, 2=xy, 3=wh (memset)
//   [3652]             done-counter (uint, memset)
//   [4096 .. 32976)    part[NAd][16]  CE partial per (na, b-group): plain stores
//   [33024 .. 34832)   noobj slot per cls block (written unconditionally)
#define OFF_CORR  0
#define OFF_GT    1824
#define OFF_ACC   3648
#define OFF_CNT   3652
#define MEMSET_FLOATS 3656
#define OFF_PART  4096
#define OFF_NOOBJ 33024

#define EXP4(v) { v.x=__expf(v.x); v.y=__expf(v.y); v.z=__expf(v.z); v.w=__expf(v.w); }

// ONE kernel, three roles by bid:
//  - bid < 48: assign (one object/thread, inline label extraction)
//  - else: transposed cls sweep: block (t,g) owns na-tile [na0,na0+16) x b in
//    [8g,8g+8); register-accumulated CE -> 16 plain stores, zero atomics.
//  - the LAST block to finish (device-scope counter) runs the final reduce.
// Single-wave blocks; no __syncthreads anywhere (same-wave DS ops are
// in-order); fences per G16 for the tail handoff.
__global__ __launch_bounds__(64) void yolo_mega(
        const float* __restrict__ conf,
        const float* __restrict__ pred_xy,
        const float* __restrict__ pred_wh,
        const float* __restrict__ cls_score,
        const float* __restrict__ true_label,
        const float* __restrict__ true_object,
        float* __restrict__ ws,
        float* __restrict__ out) {
    __shared__ float ex[1300];                  // cls path: 325 float4 window
    const int lane = threadIdx.x;
    const int bid = blockIdx.x;

    if (bid < NBLK_ASSIGN) {
        // ================= assign =================
        const float AW[5] = {0.57273f, 1.87446f, 3.33843f, 7.88282f, 9.77052f};
        const float AH[5] = {0.677385f, 2.06253f, 5.47434f, 3.52778f, 9.16828f};
        const int idx = bid * 64 + lane;        // 0..3071 exact
        float* corr = ws + OFF_CORR;
        float* gt   = ws + OFF_GT;

        // inline one-hot -> label (81 independent scalar loads, ~1 MB total)
        const float* tl = true_label + (size_t)idx * Cd;
        float labf = 0.0f;
        #pragma unroll
        for (int c0 = 0; c0 < Cd; c0++) labf += tl[c0] * (float)c0;
        int lab = (int)(labf + 0.5f);

        int b = idx / Md;
        const float4 to = ((const float4*)true_object)[idx];
        const float inv_ds = 1.0f / 32.0f;
        float gx = to.x * inv_ds, gy = to.y * inv_ds;
        float gw = to.z * inv_ds, gh = to.w * inv_ds;
        int ci = (int)gy, cj = (int)gx;         // trunc == astype(int32)
        int cell = ci * 19 + cj;
        float garea = gw * gh;

        float best_iou = -1.0f; int best = 0; bool over[5];
        #pragma unroll
        for (int a = 0; a < 5; a++) {
            float inter = fminf(AW[a], gw) * fminf(AH[a], gh);
            float iou = inter / (AW[a] * AH[a] + garea - inter + EPSF);
            over[a] = iou > IOU_THRF;
            if (iou > best_iou) { best_iou = iou; best = a; }
        }

        int base_bn = (b * Nd + cell) * 5;
        float pwb = pred_wh[(size_t)(base_bn + best) * 2 + 0];
        float phb = pred_wh[(size_t)(base_bn + best) * 2 + 1];
        float inter = fminf(pwb, gw) * fminf(phb, gh);
        float iou_pg = inter / (pwb * phb + garea - inter + EPSF);
        float sw = 2.0f - (gw * (1.0f / 19.0f)) * (gh * (1.0f / 19.0f));

        float a0 = 0.f, a1 = 0.f, a2 = 0.f, a3 = 0.f;
        #pragma unroll
        for (int a = 0; a < 5; a++) {
            bool isb = (a == best);
            if (!(isb || over[a])) continue;    // om == 0 -> untouched
            int pos = base_bn + a;
            int na  = cell * 5 + a;
            float cp = fminf(fmaxf(conf[pos], EPSF), 1.0f - EPSF);
            a0 += __logf(1.0f - cp);            // cancel base noobj term
            const float* cs = cls_score + (size_t)pos * Cd;
            atomicAdd(&corr[na], cs[Cd - 1] - cs[lab]);
            if (isb) {
                atomicAdd(&gt[na], 1.0f);
                a1 += -(iou_pg * __logf(cp) + (1.0f - iou_pg) * __logf(1.0f - cp));
                float px = pred_xy[(size_t)pos * 2 + 0], py = pred_xy[(size_t)pos * 2 + 1];
                a2 += sw * ((px - gx) * (px - gx) + (py - gy) * (py - gy));
                float pwa = pred_wh[(size_t)pos * 2 + 0], pha = pred_wh[(size_t)pos * 2 + 1];
                a3 += sw * ((pwa - gw) * (pwa - gw) + (pha - gh) * (pha - gh));
            }
        }
        #pragma unroll
        for (int off = 32; off > 0; off >>= 1) {
            a0 += __shfl_xor(a0, off, 64);
            a1 += __shfl_xor(a1, off, 64);
            a2 += __shfl_xor(a2, off, 64);
            a3 += __shfl_xor(a3, off, 64);
        }
        if (lane == 0) {
            atomicAdd(&ws[OFF_ACC + 0], a0);
            atomicAdd(&ws[OFF_ACC + 1], a1);
            atomicAdd(&ws[OFF_ACC + 2], a2);
            atomicAdd(&ws[OFF_ACC + 3], a3);
        }
    } else {
        // ================= cls sweep =================
        const int cbid = bid - NBLK_ASSIGN;
        const int r = lane >> 2, h = lane & 3;
        float4* l4 = (float4*)ex;
        const int t = cbid >> 4, g = cbid & 15;
        const int na0 = (t == NT - 1) ? (NAd - RPW) : t * RPW;  // ragged tail overlaps
        const int vmin = t * RPW;
        const bool validr = (na0 + r) >= vmin;
        const bool validc = (lane < RPW) && ((na0 + lane) >= vmin);

        float accCE = 0.0f, nb = 0.0f;

        size_t s = ((size_t)(g * 8) * NAd + na0) * Cd;
        size_t a0a = s & ~(size_t)3;
        int mcur = (int)(s & 3);
        const float4* gp = (const float4*)cls_score + (a0a >> 2);
        float4 u0 = gp[0 * 64 + lane];
        float4 u1 = gp[1 * 64 + lane];
        float4 u2 = gp[2 * 64 + lane];
        float4 u3 = gp[3 * 64 + lane];
        float4 u4 = gp[4 * 64 + lane];
        float4 u5 = gp[261 + lane];             // window [261,325); <=16B overread
        float cf = validc ? conf[(size_t)(g * 8) * NAd + na0 + lane] : 0.5f;

        for (int it = 0; it < 8; ++it) {
            EXP4(u0); EXP4(u1); EXP4(u2); EXP4(u3); EXP4(u4); EXP4(u5);
            l4[0 * 64 + lane] = u0;
            l4[1 * 64 + lane] = u1;
            l4[2 * 64 + lane] = u2;
            l4[3 * 64 + lane] = u3;
            l4[4 * 64 + lane] = u4;
            l4[261 + lane] = u5;
            __builtin_amdgcn_wave_barrier();

            // prefetch next b (overlaps the reduce)
            float4 n0 = {}, n1 = {}, n2 = {}, n3 = {}, n4 = {}, n5 = {};
            float cfn = 0.0f; int mnext = 0;
            if (it < 7) {
                int b = g * 8 + it + 1;
                s = ((size_t)b * NAd + na0) * Cd;
                a0a = s & ~(size_t)3;
                mnext = (int)(s & 3);
                gp = (const float4*)cls_score + (a0a >> 2);
                n0 = gp[0 * 64 + lane];
                n1 = gp[1 * 64 + lane];
                n2 = gp[2 * 64 + lane];
                n3 = gp[3 * 64 + lane];
                n4 = gp[4 * 64 + lane];
                n5 = gp[261 + lane];
                cfn = validc ? conf[(size_t)b * NAd + na0 + lane] : 0.5f;
            }

            const float* p = ex + mcur + r * Cd;
            float sacc = 0.0f;
            #pragma unroll
            for (int j = 0; j < 21; j++) {
                int c0 = h * 21 + j;
                int cc = c0 < 81 ? c0 : 80;
                sacc += p[cc] * ((c0 < 81) ? 1.0f : 0.0f);
            }
            sacc += __shfl_xor(sacc, 1, 64);
            sacc += __shfl_xor(sacc, 2, 64);
            if (h == 0 && validr)
                accCE += __logf(sacc) - __logf(p[80]);  // lse - raw cs[80]
            if (validc) {
                float cp = fminf(fmaxf(cf, EPSF), 1.0f - EPSF);
                nb += -__logf(1.0f - cp);
            }

            u0 = n0; u1 = n1; u2 = n2; u3 = n3; u4 = n4; u5 = n5;
            cf = cfn; mcur = mnext;
        }

        if (h == 0 && validr)
            ws[OFF_PART + (size_t)(na0 + r) * 16 + g] = accCE;
        #pragma unroll
        for (int off = 32; off > 0; off >>= 1) nb += __shfl_xor(nb, off, 64);
        if (lane == 0) ws[OFF_NOOBJ + cbid] = nb;
    }

    // ======== tail handoff: last block to finish runs the reduce ========
    __threadfence();                            // release: wbl2, device scope
    unsigned old = 0;
    if (lane == 0) old = atomicAdd((unsigned*)(ws + OFF_CNT), 1u);
    old = __shfl(old, 0, 64);
    if (old == NBLK_TOT - 1) {
        __threadfence();                        // acquire: invalidate caches
        float nsum = 0.0f;
        for (int i = lane; i < NBLK_CLS; i += 64) nsum += ws[OFF_NOOBJ + i];
        float ssum = 0.0f;
        const float4* part4 = (const float4*)(ws + OFF_PART);
        for (int na = lane; na < NAd; na += 64) {
            float4 p0 = part4[na * 4 + 0];
            float4 p1 = part4[na * 4 + 1];
            float4 p2 = part4[na * 4 + 2];
            float4 p3 = part4[na * 4 + 3];
            float ce = p0.x + p0.y + p0.z + p0.w + p1.x + p1.y + p1.z + p1.w
                     + p2.x + p2.y + p2.z + p2.w + p3.x + p3.y + p3.z + p3.w
                     + ws[OFF_CORR + na];
            ssum += ws[OFF_GT + na] * ce;
        }
        #pragma unroll
        for (int off = 32; off > 0; off >>= 1) {
            nsum += __shfl_xor(nsum, off, 64);
            ssum += __shfl_xor(ssum, off, 64);
        }
        if (lane == 0) {
            const float invB = 1.0f / (float)Bsz;
            float noobj = 1.0f * (nsum + ws[OFF_ACC + 0]) * invB;  // base + cancels
            float obj   = 5.0f * ws[OFF_ACC + 1] * invB;
            float xy    = 5.0f * ws[OFF_ACC + 2] * invB;
            float wh    = 5.0f * ws[OFF_ACC + 3] * invB;
            float score = 5.0f * ssum * invB;
            out[0] = noobj + obj + xy + wh + score;
            out[1] = noobj;
            out[2] = obj;
            out[3] = score;
            out[4] = xy;
            out[5] = wh;
        }
    }
}

extern "C" void kernel_launch(void* const* d_in, const int* in_sizes, int n_in,
                              void* d_out, int out_size, void* d_ws, size_t ws_size,
                              hipStream_t stream) {
    // inputs: 0=epoch(unused), 1=conf, 2=pred_xy, 3=pred_wh, 4=cls_score,
    //         5=true_label, 6=true_object, 7=fm_cord(unused - cancels out)
    const float* conf    = (const float*)d_in[1];
    const float* pred_xy = (const float*)d_in[2];
    const float* pred_wh = (const float*)d_in[3];
    const float* cls     = (const float*)d_in[4];
    const float* tlabel  = (const float*)d_in[5];
    const float* tobject = (const float*)d_in[6];
    float* ws  = (float*)d_ws;
    float* out = (float*)d_out;

    hipMemsetAsync(ws, 0, MEMSET_FLOATS * sizeof(float), stream);

    yolo_mega<<<NBLK_TOT, 64, 0, stream>>>(conf, pred_xy, pred_wh, cls,
                                           tlabel, tobject, ws, out);
}

// Round 10
// 134.870 us; speedup vs baseline: 1.5152x; 1.5152x over previous
//
#include <hip/hip_runtime.h>

#define Bsz 128
#define Cd 81
#define Md 24
#define Nd 361
#define NAd 1805
#define RPW 16                    // na-rows per tile / rows per chunk
#define NT 113                    // na tiles (112 full + 1 ragged, na0=1789)
#define NBLK_CLS (NT*16)          // 1808 cls blocks: (tile t, b-group g of 8)
#define NBLK_ASSIGN 48            // 48 x 64 = 3072 objects, one per thread
#define NBLK_TOT (NBLK_CLS + NBLK_ASSIGN)   // 1856
#define NOBJ (Bsz*Md)             // 3072
#define EPSF 1e-7f
#define IOU_THRF 0.6f

// ws float layout:
//   [0 .. 1805)        corr[NAd]      assign CE corrections (memset)
//   [1824 .. 3629)     gt[NAd]        (memset)
//   [3648 .. 3652)     acc: 0=noobj-cancel, 1=obj, 2=xy, 3=wh (memset)
//   [4096 .. 32976)    part[NAd][16]  CE partial per (na, b-group): plain stores,
//                                     every live slot written exactly once
//   [33024 .. 34832)   noobj slot per cls block (written unconditionally)
#define OFF_CORR  0
#define OFF_GT    1824
#define OFF_ACC   3648
#define MEMSET_FLOATS 3652
#define OFF_PART  4096
#define OFF_NOOBJ 33024

// native clang vector type: __builtin_nontemporal_load needs this, not
// HIP_vector_type (struct wrapper) -- that was R9's compile failure.
typedef float vf4 __attribute__((ext_vector_type(4)));

#define EXP4(v) { v.x=__expf(v.x); v.y=__expf(v.y); v.z=__expf(v.z); v.w=__expf(v.w); }
#define NTL4(p) __builtin_nontemporal_load(p)

// Fused sweep+assign, NO fences/counters (R8's per-block __threadfence ->
// buffer_wbl2 regressed 2x). All cls_score/conf streaming uses NON-TEMPORAL
// loads: the harness's d2d restore leaves ~32MB of cls_score dirty across
// the 8 per-XCD L2s; normal reads from other XCDs hit the slow cross-XCD
// coherence path (the structure-independent ~1.5 TB/s read wall of R1-R8).
// nt bypasses L2 for this single-touch stream.
__global__ __launch_bounds__(64) void yolo_sweep(
        const float* __restrict__ conf,
        const float* __restrict__ pred_xy,
        const float* __restrict__ pred_wh,
        const float* __restrict__ cls_score,
        const float* __restrict__ true_label,
        const float* __restrict__ true_object,
        float* __restrict__ ws) {
    __shared__ float ex[1300];                  // 325 float4 window
    const int lane = threadIdx.x;
    const int bid = blockIdx.x;

    if (bid < NBLK_CLS) {
        // ================= cls sweep =================
        const int r = lane >> 2, h = lane & 3;
        vf4* l4 = (vf4*)ex;
        const int t = bid >> 4, g = bid & 15;
        const int na0 = (t == NT - 1) ? (NAd - RPW) : t * RPW;  // ragged tail overlaps
        const int vmin = t * RPW;
        const bool validr = (na0 + r) >= vmin;
        const bool validc = (lane < RPW) && ((na0 + lane) >= vmin);

        float accCE = 0.0f, nb = 0.0f;

        size_t s = ((size_t)(g * 8) * NAd + na0) * Cd;
        size_t a0a = s & ~(size_t)3;
        int mcur = (int)(s & 3);
        const vf4* gp = (const vf4*)cls_score + (a0a >> 2);
        vf4 u0 = NTL4(gp + 0 * 64 + lane);
        vf4 u1 = NTL4(gp + 1 * 64 + lane);
        vf4 u2 = NTL4(gp + 2 * 64 + lane);
        vf4 u3 = NTL4(gp + 3 * 64 + lane);
        vf4 u4 = NTL4(gp + 4 * 64 + lane);
        vf4 u5 = NTL4(gp + 261 + lane);         // window [261,325); <=16B overread
        float cf = validc ? __builtin_nontemporal_load(conf + (size_t)(g * 8) * NAd + na0 + lane)
                          : 0.5f;

        for (int it = 0; it < 8; ++it) {
            EXP4(u0); EXP4(u1); EXP4(u2); EXP4(u3); EXP4(u4); EXP4(u5);
            l4[0 * 64 + lane] = u0;
            l4[1 * 64 + lane] = u1;
            l4[2 * 64 + lane] = u2;
            l4[3 * 64 + lane] = u3;
            l4[4 * 64 + lane] = u4;
            l4[261 + lane] = u5;                // dup region carries identical data
            __builtin_amdgcn_wave_barrier();

            // prefetch next b (overlaps the reduce)
            vf4 n0 = {}, n1 = {}, n2 = {}, n3 = {}, n4 = {}, n5 = {};
            float cfn = 0.0f; int mnext = 0;
            if (it < 7) {
                int b = g * 8 + it + 1;
                s = ((size_t)b * NAd + na0) * Cd;
                a0a = s & ~(size_t)3;
                mnext = (int)(s & 3);
                gp = (const vf4*)cls_score + (a0a >> 2);
                n0 = NTL4(gp + 0 * 64 + lane);
                n1 = NTL4(gp + 1 * 64 + lane);
                n2 = NTL4(gp + 2 * 64 + lane);
                n3 = NTL4(gp + 3 * 64 + lane);
                n4 = NTL4(gp + 4 * 64 + lane);
                n5 = NTL4(gp + 261 + lane);
                if (validc)
                    cfn = __builtin_nontemporal_load(conf + (size_t)b * NAd + na0 + lane);
            }

            // reduce current chunk from LDS: 4 lanes per row
            const float* p = ex + mcur + r * Cd;
            float sacc = 0.0f;
            #pragma unroll
            for (int j = 0; j < 21; j++) {
                int c0 = h * 21 + j;
                int cc = c0 < 81 ? c0 : 80;
                sacc += p[cc] * ((c0 < 81) ? 1.0f : 0.0f);
            }
            sacc += __shfl_xor(sacc, 1, 64);
            sacc += __shfl_xor(sacc, 2, 64);
            if (h == 0 && validr)
                accCE += __logf(sacc) - __logf(p[80]);  // lse - raw cs[80]
            if (validc) {
                float cp = fminf(fmaxf(cf, EPSF), 1.0f - EPSF);
                nb += -__logf(1.0f - cp);
            }

            u0 = n0; u1 = n1; u2 = n2; u3 = n3; u4 = n4; u5 = n5;
            cf = cfn; mcur = mnext;
        }

        if (h == 0 && validr)
            ws[OFF_PART + (size_t)(na0 + r) * 16 + g] = accCE;   // unique slot
        #pragma unroll
        for (int off = 32; off > 0; off >>= 1) nb += __shfl_xor(nb, off, 64);
        if (lane == 0) ws[OFF_NOOBJ + bid] = nb;
    } else {
        // ================= assign =================
        const float AW[5] = {0.57273f, 1.87446f, 3.33843f, 7.88282f, 9.77052f};
        const float AH[5] = {0.677385f, 2.06253f, 5.47434f, 3.52778f, 9.16828f};
        const int idx = (bid - NBLK_CLS) * 64 + lane;   // 0..3071 exact
        float* corr = ws + OFF_CORR;
        float* gt   = ws + OFF_GT;

        // inline one-hot -> label (81 independent scalar loads)
        const float* tl = true_label + (size_t)idx * Cd;
        float labf = 0.0f;
        #pragma unroll
        for (int c0 = 0; c0 < Cd; c0++) labf += tl[c0] * (float)c0;
        int lab = (int)(labf + 0.5f);

        int b = idx / Md;
        const float4 to = ((const float4*)true_object)[idx];
        const float inv_ds = 1.0f / 32.0f;
        float gx = to.x * inv_ds, gy = to.y * inv_ds;
        float gw = to.z * inv_ds, gh = to.w * inv_ds;
        int ci = (int)gy, cj = (int)gx;         // trunc == astype(int32)
        int cell = ci * 19 + cj;
        float garea = gw * gh;

        float best_iou = -1.0f; int best = 0; bool over[5];
        #pragma unroll
        for (int a = 0; a < 5; a++) {
            float inter = fminf(AW[a], gw) * fminf(AH[a], gh);
            float iou = inter / (AW[a] * AH[a] + garea - inter + EPSF);
            over[a] = iou > IOU_THRF;
            if (iou > best_iou) { best_iou = iou; best = a; }
        }

        int base_bn = (b * Nd + cell) * 5;
        float pwb = pred_wh[(size_t)(base_bn + best) * 2 + 0];
        float phb = pred_wh[(size_t)(base_bn + best) * 2 + 1];
        float inter = fminf(pwb, gw) * fminf(phb, gh);
        float iou_pg = inter / (pwb * phb + garea - inter + EPSF);
        float sw = 2.0f - (gw * (1.0f / 19.0f)) * (gh * (1.0f / 19.0f));

        float a0 = 0.f, a1 = 0.f, a2 = 0.f, a3 = 0.f;
        #pragma unroll
        for (int a = 0; a < 5; a++) {
            bool isb = (a == best);
            if (!(isb || over[a])) continue;    // om == 0 -> untouched
            int pos = base_bn + a;
            int na  = cell * 5 + a;
            float cp = fminf(fmaxf(conf[pos], EPSF), 1.0f - EPSF);
            a0 += __logf(1.0f - cp);            // cancel base noobj term
            const float* cs = cls_score + (size_t)pos * Cd;
            atomicAdd(&corr[na], cs[Cd - 1] - cs[lab]);
            if (isb) {
                atomicAdd(&gt[na], 1.0f);
                a1 += -(iou_pg * __logf(cp) + (1.0f - iou_pg) * __logf(1.0f - cp));
                float px = pred_xy[(size_t)pos * 2 + 0], py = pred_xy[(size_t)pos * 2 + 1];
                a2 += sw * ((px - gx) * (px - gx) + (py - gy) * (py - gy));
                float pwa = pred_wh[(size_t)pos * 2 + 0], pha = pred_wh[(size_t)pos * 2 + 1];
                a3 += sw * ((pwa - gw) * (pwa - gw) + (pha - gh) * (pha - gh));
            }
        }
        #pragma unroll
        for (int off = 32; off > 0; off >>= 1) {
            a0 += __shfl_xor(a0, off, 64);
            a1 += __shfl_xor(a1, off, 64);
            a2 += __shfl_xor(a2, off, 64);
            a3 += __shfl_xor(a3, off, 64);
        }
        if (lane == 0) {
            atomicAdd(&ws[OFF_ACC + 0], a0);
            atomicAdd(&ws[OFF_ACC + 1], a1);
            atomicAdd(&ws[OFF_ACC + 2], a2);
            atomicAdd(&ws[OFF_ACC + 3], a3);
        }
    }
}

// Single block, coalesced L2-resident reductions only (~140 KB of reads).
__global__ __launch_bounds__(1024) void yolo_reduce(
        const float* __restrict__ ws, float* __restrict__ out) {
    __shared__ float red[2][16];
    const int tid = threadIdx.x;
    float nsum = 0.0f;
    for (int i = tid; i < NBLK_CLS; i += 1024) nsum += ws[OFF_NOOBJ + i];
    float ssum = 0.0f;
    const float4* part4 = (const float4*)(ws + OFF_PART);
    for (int na = tid; na < NAd; na += 1024) {
        float4 p0 = part4[na * 4 + 0];
        float4 p1 = part4[na * 4 + 1];
        float4 p2 = part4[na * 4 + 2];
        float4 p3 = part4[na * 4 + 3];
        float ce = p0.x + p0.y + p0.z + p0.w + p1.x + p1.y + p1.z + p1.w
                 + p2.x + p2.y + p2.z + p2.w + p3.x + p3.y + p3.z + p3.w
                 + ws[OFF_CORR + na];
        ssum += ws[OFF_GT + na] * ce;
    }

    float v[2] = {nsum, ssum};
    #pragma unroll
    for (int k = 0; k < 2; k++) {
        float x = v[k];
        #pragma unroll
        for (int off = 32; off > 0; off >>= 1) x += __shfl_xor(x, off, 64);
        if ((tid & 63) == 0) red[k][tid >> 6] = x;
    }
    __syncthreads();
    if (tid == 0) {
        float t0 = 0.f, t1 = 0.f;
        #pragma unroll
        for (int w = 0; w < 16; w++) { t0 += red[0][w]; t1 += red[1][w]; }
        const float invB = 1.0f / (float)Bsz;
        float noobj = 1.0f * (t0 + ws[OFF_ACC + 0]) * invB;   // base + cancels
        float obj   = 5.0f * ws[OFF_ACC + 1] * invB;
        float xy    = 5.0f * ws[OFF_ACC + 2] * invB;
        float wh    = 5.0f * ws[OFF_ACC + 3] * invB;
        float score = 5.0f * t1 * invB;
        out[0] = noobj + obj + xy + wh + score;
        out[1] = noobj;
        out[2] = obj;
        out[3] = score;
        out[4] = xy;
        out[5] = wh;
    }
}

extern "C" void kernel_launch(void* const* d_in, const int* in_sizes, int n_in,
                              void* d_out, int out_size, void* d_ws, size_t ws_size,
                              hipStream_t stream) {
    // inputs: 0=epoch(unused), 1=conf, 2=pred_xy, 3=pred_wh, 4=cls_score,
    //         5=true_label, 6=true_object, 7=fm_cord(unused - cancels out)
    const float* conf    = (const float*)d_in[1];
    const float* pred_xy = (const float*)d_in[2];
    const float* pred_wh = (const float*)d_in[3];
    const float* cls     = (const float*)d_in[4];
    const float* tlabel  = (const float*)d_in[5];
    const float* tobject = (const float*)d_in[6];
    float* ws  = (float*)d_ws;
    float* out = (float*)d_out;

    hipMemsetAsync(ws, 0, MEMSET_FLOATS * sizeof(float), stream);

    yolo_sweep<<<NBLK_TOT, 64, 0, stream>>>(conf, pred_xy, pred_wh, cls,
                                            tlabel, tobject, ws);

    yolo_reduce<<<1, 1024, 0, stream>>>(ws, out);
}